// Round 6
// baseline (142.120 us; speedup 1.0000x reference)
//
#include <hip/hip_runtime.h>

typedef unsigned char u8;
typedef float fp32x4 __attribute__((ext_vector_type(4)));
typedef long lx2 __attribute__((ext_vector_type(2)));

#define BS 4096
#define NROW 8192
#define D 512
#define TILE 128
#define NB (NROW / TILE)          // 64 block-rows/cols
#define NBLK (NB * (NB + 1) / 2)  // 2080 upper-triangle tiles
#define NPBLK 512                 // 2 blocks/CU (64.2 KB LDS each)
#define NTHR 256                  // 4 waves
#define KITER 4                   // K split into 4 iters of BK=128
#define INV_T 10.0f

// Packed An layout (unchanged; verified R2: bank conflicts 1.28e7 -> 2.1e6).
// 8-byte chunk L = k>>3 of row r:
//   off(r, L) = (r>>4)*8192 + (L>>3)*1024 + (r&15)*64
//             + (((L&3) ^ ((r&15)>>2)) << 4) + (((L>>2)&1) << 3)
// A 16-row group x 64-k "p-block" = 1024 contiguous bytes. K-iter kk covers
// p = 2kk, 2kk+1 -> per 128-row strip: 8 gi-groups x 2 KB = 16 KB staged.
// Consumer lane (fr=l&15, h=l>>4): ds_read_b128 at gi*2048 + pp*1024 +
// fr*64 + ((h^(fr>>2))&3)*16 covers ks=2p, 2p+1 conflict-free.

__device__ __forceinline__ void g2l16(const void* g, void* l) {
  __builtin_amdgcn_global_load_lds(
      (const __attribute__((address_space(1))) unsigned int*)g,
      (__attribute__((address_space(3))) unsigned int*)l, 16, 0, 0);
}

// stage one 16 KB K-iter part of a 128-row strip; 4 g2l16 per thread.
// LDS part layout: [gi:8][pp:2][1024] (linear); global: gi*8192 + kk*2048 + rest
__device__ __forceinline__ void stage_part(const u8* __restrict__ strip, int kk,
                                           u8* __restrict__ dst, int tid) {
#pragma unroll
  for (int c = 0; c < 4; ++c) {
    const int l = tid * 16 + c * 4096;  // 0..16383
    g2l16(strip + ((l >> 11) << 13) + (kk << 11) + (l & 2047), dst + l);
  }
}

// Wave-per-row normalize -> fp8 e4m3, packed+swizzled layout.
// Also zeroes den/posAcc/done (ws is re-poisoned before every launch).
__global__ __launch_bounds__(256) void normalize_k(
    const float* __restrict__ zi, const float* __restrict__ zj,
    u8* __restrict__ An, float* __restrict__ den, float* __restrict__ posAcc,
    int* __restrict__ done) {
  const int lane = threadIdx.x & 63;
  const int wave = threadIdx.x >> 6;
  const int r = blockIdx.x * 4 + wave;
  const float* src = (r < BS) ? (zi + (size_t)r * D) : (zj + (size_t)(r - BS) * D);
  const float4 v0 = ((const float4*)src)[lane * 2];
  const float4 v1 = ((const float4*)src)[lane * 2 + 1];
  float ss = v0.x * v0.x + v0.y * v0.y + v0.z * v0.z + v0.w * v0.w +
             v1.x * v1.x + v1.y * v1.y + v1.z * v1.z + v1.w * v1.w;
#pragma unroll
  for (int off = 1; off < 64; off <<= 1) ss += __shfl_xor(ss, off);
  const float inv = 1.0f / fmaxf(sqrtf(ss), 1e-8f);
  int lo = __builtin_amdgcn_cvt_pk_fp8_f32(v0.x * inv, v0.y * inv, 0, false);
  lo = __builtin_amdgcn_cvt_pk_fp8_f32(v0.z * inv, v0.w * inv, lo, true);
  int hi = __builtin_amdgcn_cvt_pk_fp8_f32(v1.x * inv, v1.y * inv, 0, false);
  hi = __builtin_amdgcn_cvt_pk_fp8_f32(v1.z * inv, v1.w * inv, hi, true);
  const int r16 = r & 15;
  const int off = ((r >> 4) << 13) + ((lane >> 3) << 10) + (r16 << 6) +
                  ((((lane & 3) ^ (r16 >> 2)) & 3) << 4) + (((lane >> 2) & 1) << 3);
  *(int2*)(An + off) = make_int2(lo, hi);
  if (lane == 0) den[r] = 0.0f;
  if (r == 0 && lane == 0) { posAcc[0] = 0.0f; *done = 0; }
}

// Persistent triangle GEMM, T3-style pipelined K-iters:
//   per iter: issue next-iter DMA (into other buffer) -> ds-read + 64 MFMA
//   on current buffer -> (kk==3: epilogue) -> one __syncthreads drain.
// Stages are issued a full MFMA-phase (+epilogue) before their drain, so
// the barrier wait is short. 2 independent blocks/CU cross-hide the rest.
__global__ __launch_bounds__(NTHR) void gemm_expsum(
    const u8* __restrict__ An, float* __restrict__ den,
    float* __restrict__ posAcc, int* __restrict__ done,
    float* __restrict__ out) {
  __shared__ __align__(16) u8 sBuf[2][2][16384];  // [dbuf][A|B][16KB] = 64 KB
  __shared__ float redbuf[4];
  __shared__ int lastFlag;

  const int tid = threadIdx.x;
  const int lane = tid & 63;
  const int wave = tid >> 6;
  const int wr = wave >> 1;  // 64-row band within the 128x128 tile
  const int wc = wave & 1;   // 64-col band
  const int fr = lane & 15;
  const int h = lane >> 4;

  // contiguous chunk [t0, t1) of triangle tiles (4 or 5 per block)
  const int t0 = (int)(((long)blockIdx.x * NBLK) >> 9);
  const int t1 = (int)(((long)(blockIdx.x + 1) * NBLK) >> 9);

  int rem = t0, bi = 0;
  while (rem >= NB - bi) { rem -= NB - bi; ++bi; }
  int bj = bi + rem;

  // prologue: stage (t0, kk=0) into buf 0
  stage_part(An + (size_t)bi * 65536, 0, &sBuf[0][0][0], tid);
  stage_part(An + (size_t)bj * 65536, 0, &sBuf[0][1][0], tid);
  __syncthreads();  // full drain once

  const int fbase = fr * 64 + ((h ^ (fr >> 2)) & 3) * 16;
  int cur = 0;
  fp32x4 acc[4][4] = {};

  for (int t = t0; t < t1; ++t) {
#pragma unroll
    for (int kk = 0; kk < KITER; ++kk) {
      // ---- issue next iter's staging into the other buffer ----
      int nbi = bi, nbj = bj, nkk = kk + 1;
      if (nkk == KITER) {
        nkk = 0;
        ++nbj;
        if (nbj == NB) { ++nbi; nbj = nbi; }
      }
      const bool more = (kk < KITER - 1) || (t + 1 < t1);
      if (more) {
        stage_part(An + (size_t)nbi * 65536, nkk, &sBuf[cur ^ 1][0][0], tid);
        stage_part(An + (size_t)nbj * 65536, nkk, &sBuf[cur ^ 1][1][0], tid);
      }

      // ---- fragment reads from current buffer ----
      const u8* bA = &sBuf[cur][0][0] + wr * 8192 + fbase;  // 4 gi-groups
      const u8* bB = &sBuf[cur][1][0] + wc * 8192 + fbase;
      lx2 a0[4], a1[4], b0[4], b1[4];
#pragma unroll
      for (int i = 0; i < 4; ++i) {
        a0[i] = *(const lx2*)(bA + i * 2048);
        a1[i] = *(const lx2*)(bA + i * 2048 + 1024);
        b0[i] = *(const lx2*)(bB + i * 2048);
        b1[i] = *(const lx2*)(bB + i * 2048 + 1024);
      }

      // ---- 64 MFMA (T5: keep matrix pipe favored) ----
      __builtin_amdgcn_s_setprio(1);
#pragma unroll
      for (int i = 0; i < 4; ++i)
#pragma unroll
        for (int j = 0; j < 4; ++j)
          acc[i][j] = __builtin_amdgcn_mfma_f32_16x16x32_fp8_fp8(
              a0[i][0], b0[j][0], acc[i][j], 0, 0, 0);
#pragma unroll
      for (int i = 0; i < 4; ++i)
#pragma unroll
        for (int j = 0; j < 4; ++j)
          acc[i][j] = __builtin_amdgcn_mfma_f32_16x16x32_fp8_fp8(
              a0[i][1], b0[j][1], acc[i][j], 0, 0, 0);
#pragma unroll
      for (int i = 0; i < 4; ++i)
#pragma unroll
        for (int j = 0; j < 4; ++j)
          acc[i][j] = __builtin_amdgcn_mfma_f32_16x16x32_fp8_fp8(
              a1[i][0], b1[j][0], acc[i][j], 0, 0, 0);
#pragma unroll
      for (int i = 0; i < 4; ++i)
#pragma unroll
        for (int j = 0; j < 4; ++j)
          acc[i][j] = __builtin_amdgcn_mfma_f32_16x16x32_fp8_fp8(
              a1[i][1], b1[j][1], acc[i][j], 0, 0, 0);
      __builtin_amdgcn_s_setprio(0);

      // ---- epilogue on last K-iter (covers the in-flight DMA) ----
      if (kk == KITER - 1) {
        const bool diag = (bi == bj);
        const int rowBase = bi * TILE;
        const int colBase = bj * TILE;
        const int rq = h * 4;
        float posPart = 0.0f;
        float colAcc[4] = {0.0f, 0.0f, 0.0f, 0.0f};
#pragma unroll
        for (int i = 0; i < 4; ++i) {
          const int rbase = rowBase + wr * 64 + i * 16 + rq;
          float rs[4] = {0.0f, 0.0f, 0.0f, 0.0f};
#pragma unroll
          for (int j = 0; j < 4; ++j) {
            const int colg = colBase + wc * 64 + j * 16 + fr;
            fp32x4 v = acc[i][j];
#pragma unroll
            for (int rg = 0; rg < 4; ++rg) {
              const int rowg = rbase + rg;
              const float sv = v[rg] * INV_T;
              float e = __expf(sv);
              if (diag && rowg == colg) e = 0.0f;  // exclude exact diagonal
              rs[rg] += e;
              colAcc[j] += e;
              if (colg == rowg + BS) posPart += sv;  // upper copy; x2 later
            }
          }
#pragma unroll
          for (int rg = 0; rg < 4; ++rg) {
            float s = rs[rg];
            s += __shfl_xor(s, 1);
            s += __shfl_xor(s, 2);
            s += __shfl_xor(s, 4);
            s += __shfl_xor(s, 8);
            if (fr == 0) atomicAdd(&den[rbase + rg], s);
          }
        }
        if (!diag) {
#pragma unroll
          for (int j = 0; j < 4; ++j) {
            float c = colAcc[j];
            c += __shfl_xor(c, 16);
            c += __shfl_xor(c, 32);
            if (h == 0) atomicAdd(&den[colBase + wc * 64 + j * 16 + fr], c);
          }
        }
        posPart += __shfl_xor(posPart, 1);
        posPart += __shfl_xor(posPart, 2);
        posPart += __shfl_xor(posPart, 4);
        posPart += __shfl_xor(posPart, 8);
        posPart += __shfl_xor(posPart, 16);
        posPart += __shfl_xor(posPart, 32);
        if (lane == 0 && posPart != 0.0f) atomicAdd(posAcc, posPart);
#pragma unroll
        for (int i = 0; i < 4; ++i)
#pragma unroll
          for (int j = 0; j < 4; ++j) acc[i][j] = (fp32x4){0, 0, 0, 0};
      }

      __syncthreads();  // drains this iter's DMA; next iter's buffer ready
      cur ^= 1;
      bi = nbi;
      bj = nbj;
    }
  }

  // ---- fused finalize: last block to finish computes the loss ----
  __threadfence();  // device-scope: den/posAcc atomics visible
  if (tid == 0) lastFlag = (atomicAdd(done, 1) == NPBLK - 1);
  __syncthreads();
  if (lastFlag) {
    float s = 0.0f;
    for (int i = tid; i < NROW; i += NTHR)
      s += logf(__hip_atomic_load(&den[i], __ATOMIC_RELAXED,
                                  __HIP_MEMORY_SCOPE_AGENT));
#pragma unroll
    for (int off = 1; off < 64; off <<= 1) s += __shfl_xor(s, off);
    if (lane == 0) redbuf[wave] = s;
    __syncthreads();
    if (tid == 0) {
      float tot = redbuf[0] + redbuf[1] + redbuf[2] + redbuf[3];
      const float pos = __hip_atomic_load(posAcc, __ATOMIC_RELAXED,
                                          __HIP_MEMORY_SCOPE_AGENT);
      // each unordered positive pair was counted once -> double it
      out[0] = (tot - 2.0f * pos) * (1.0f / (float)NROW);
    }
  }
}

extern "C" void kernel_launch(void* const* d_in, const int* in_sizes, int n_in,
                              void* d_out, int out_size, void* d_ws, size_t ws_size,
                              hipStream_t stream) {
  const float* zi = (const float*)d_in[0];
  const float* zj = (const float*)d_in[1];
  float* out = (float*)d_out;

  u8* An = (u8*)d_ws;                                      // 4 MB packed fp8
  float* den = (float*)((char*)d_ws + (size_t)NROW * D);   // 8192 fp32
  float* posAcc = den + NROW;                              // 1 fp32
  int* done = (int*)(posAcc + 1);                          // 1 int

  normalize_k<<<NROW / 4, 256, 0, stream>>>(zi, zj, An, den, posAcc, done);
  gemm_expsum<<<NPBLK, NTHR, 0, stream>>>(An, den, posAcc, done, out);
}